// Round 4
// baseline (1014.475 us; speedup 1.0000x reference)
//
#include <hip/hip_runtime.h>
#include <hip/hip_bf16.h>

typedef unsigned short u16;
typedef __attribute__((ext_vector_type(4))) float f32x4;
typedef __attribute__((ext_vector_type(8))) short bf16x8;
typedef __attribute__((ext_vector_type(4))) unsigned short u16x4;

#define N 8192
#define LOG2E 1.4426950408889634f

__device__ __forceinline__ float bf2f(u16 u){
  union { float f; unsigned int i; } v; v.i = ((unsigned int)u) << 16; return v.f;
}
__device__ __forceinline__ u16 f2bf(float f){
  union { float f; unsigned int i; } v; v.f = f;
  unsigned int r = v.i + 0x7fffu + ((v.i >> 16) & 1u);
  return (u16)(r >> 16);
}
__device__ __forceinline__ f32x4 mfma16(bf16x8 a, bf16x8 b, f32x4 c){
  return __builtin_amdgcn_mfma_f32_16x16x32_bf16(a, b, c, 0, 0, 0);
}
__device__ __forceinline__ unsigned int fkey_enc(float f){
  unsigned int u = __float_as_uint(f);
  return (u & 0x80000000u) ? ~u : (u | 0x80000000u);
}
__device__ __forceinline__ float fkey_dec(unsigned int k){
  unsigned int u = (k & 0x80000000u) ? (k ^ 0x80000000u) : ~k;
  return __uint_as_float(u);
}

// ---------------- pack adj -> bitmask [N][1024B], bytes permuted [0,4,1,5,2,6,3,7] ----------------
__global__ __launch_bounds__(256) void k_pack(const int* __restrict__ adj,
                                              unsigned long long* __restrict__ packed){
  const int wid = blockIdx.x * 4 + (threadIdx.x >> 6);
  const int lane = threadIdx.x & 63;
  const size_t base = (size_t)wid * 128;
  #pragma unroll 4
  for (int g = 0; g < 128; ++g){
    const size_t grp = base + g;
    const int v = adj[grp * 64 + lane];
    const unsigned long long m = __ballot(v != 0);
    if (lane == 0){
      const unsigned int lo = (unsigned int)m, hi = (unsigned int)(m >> 32);
      const unsigned int olo = __builtin_amdgcn_perm(hi, lo, 0x05010400u);
      const unsigned int ohi = __builtin_amdgcn_perm(hi, lo, 0x07030602u);
      packed[grp] = ((unsigned long long)ohi << 32) | olo;
    }
  }
}

// ---------------- fused prep: x->bf16(+comb), 4 transposes, wa vectors, zero-init ----------------
__global__ __launch_bounds__(256) void k_prep(
    const float* __restrict__ x, const float* __restrict__ Wh, const float* __restrict__ Wo,
    const float* __restrict__ g1, const float* __restrict__ g2,
    const float* __restrict__ ah, const float* __restrict__ ao,
    u16* __restrict__ xbf, u16* __restrict__ comb,
    u16* __restrict__ wth, u16* __restrict__ wot,
    u16* __restrict__ g1t, u16* __restrict__ g2t,
    float* __restrict__ wa, unsigned int* __restrict__ fkey, float* __restrict__ csum)
{
  const int b = blockIdx.x, t = threadIdx.x;
  if (b < 1024){                                  // x -> xbf + comb[:, :128]
    const int idx = b * 256 + t;
    f32x4 v = ((const f32x4*)x)[idx];
    u16x4 h;
    #pragma unroll
    for (int e = 0; e < 4; ++e) h[e] = f2bf(v[e]);
    ((u16x4*)xbf)[idx] = h;
    const int i = idx >> 5, c4 = (idx & 31) * 4;
    *(u16x4*)(comb + (size_t)i * 256 + c4) = h;
  } else if (b < 1152){                           // Wh^T (2 heads)
    const int rel = (b - 1024) * 256 + t;
    const int head = rel >> 14, win = rel & 16383;
    const int n = win >> 7, k = win & 127;
    wth[rel] = f2bf(Wh[(head << 14) + k * 128 + n]);
  } else if (b < 1280){                           // Wo^T
    const int rel = (b - 1152) * 256 + t;
    const int n = rel >> 8, k = rel & 255;
    wot[rel] = f2bf(Wo[k * 128 + n]);
  } else if (b < 1536){                           // g1^T
    const int rel = (b - 1280) * 256 + t;
    const int n = rel >> 8, k = rel & 255;
    g1t[rel] = f2bf(g1[k * 256 + n]);
  } else if (b < 1664){                           // g2^T
    const int rel = (b - 1536) * 256 + t;
    const int n = rel >> 8, k = rel & 255;
    g2t[rel] = f2bf(g2[k * 128 + n]);
  } else if (b < 1667){                           // wa vectors
    const int z = b - 1664;
    if (z < 2){
      if (t < 128){
        float a1 = 0.f, a2 = 0.f;
        for (int c = 0; c < 128; ++c){
          const float w = Wh[(size_t)z * 16384 + t * 128 + c];
          a1 += w * ah[z * 256 + c];
          a2 += w * ah[z * 256 + 128 + c];
        }
        wa[z * 128 + t] = a1; wa[256 + z * 128 + t] = a2;
      }
    } else {
      if (t < 256){
        float a1 = 0.f, a2 = 0.f;
        for (int c = 0; c < 128; ++c){
          const float w = Wo[(size_t)t * 128 + c];
          a1 += w * ao[c];
          a2 += w * ao[128 + c];
        }
        wa[512 + t] = a1; wa[768 + t] = a2;
      }
    }
  } else {                                        // zero-init csum + fkey
    if (t < 128) csum[t] = 0.f;
    if (t < 4) fkey[t] = 0u;
  }
}

// ---------------- gemv layer1: f1s/f2s = (x @ wa) * log2e, + keyed atomic max of f2 ----------------
__global__ __launch_bounds__(256) void k_gemv1(const float* __restrict__ x, const float* __restrict__ wa,
                                               float* __restrict__ f1s, float* __restrict__ f2s,
                                               unsigned int* __restrict__ fkey){
  const int h = blockIdx.y;
  const float* wa1 = wa + h * 128;
  const float* wa2 = wa + 256 + h * 128;
  const int lane = threadIdx.x & 63, w = threadIdx.x >> 6;
  const int r16 = lane & 15, g4 = lane >> 4;
  const int row = blockIdx.x * 16 + w * 4 + g4;
  const float* xr = x + (size_t)row * 128 + r16 * 8;
  f32x4 x0 = *(const f32x4*)(xr);
  f32x4 x1 = *(const f32x4*)(xr + 4);
  f32x4 wA0 = *(const f32x4*)(wa1 + r16 * 8);
  f32x4 wA1 = *(const f32x4*)(wa1 + r16 * 8 + 4);
  f32x4 wB0 = *(const f32x4*)(wa2 + r16 * 8);
  f32x4 wB1 = *(const f32x4*)(wa2 + r16 * 8 + 4);
  float d1 = 0.f, d2 = 0.f;
  #pragma unroll
  for (int e = 0; e < 4; ++e){
    d1 += x0[e] * wA0[e] + x1[e] * wA1[e];
    d2 += x0[e] * wB0[e] + x1[e] * wB1[e];
  }
  d1 += __shfl_xor(d1, 1); d1 += __shfl_xor(d1, 2); d1 += __shfl_xor(d1, 4); d1 += __shfl_xor(d1, 8);
  d2 += __shfl_xor(d2, 1); d2 += __shfl_xor(d2, 2); d2 += __shfl_xor(d2, 4); d2 += __shfl_xor(d2, 8);
  const float d1s = d1 * LOG2E, d2s = d2 * LOG2E;
  if (r16 == 0){
    f1s[(size_t)h * N + row] = d1s;
    f2s[(size_t)h * N + row] = d2s;
  }
  float m = d2s;
  m = fmaxf(m, __shfl_xor(m, 16)); m = fmaxf(m, __shfl_xor(m, 32));
  if (lane == 0) atomicMax(fkey + h, fkey_enc(m));
}

// ---------------- gemv layer2 (+ keyed atomic max) ----------------
__global__ __launch_bounds__(256) void k_gemv2(const u16* __restrict__ hbf,
                                               const float* __restrict__ wao1, const float* __restrict__ wao2,
                                               float* __restrict__ f1s, float* __restrict__ f2s,
                                               unsigned int* __restrict__ fkey){
  const int lane = threadIdx.x & 63, w = threadIdx.x >> 6;
  const int r16 = lane & 15, g4 = lane >> 4;
  const int row = blockIdx.x * 16 + w * 4 + g4;
  bf16x8 h0 = *(const bf16x8*)(hbf + (size_t)row * 256 + r16 * 16);
  bf16x8 h1 = *(const bf16x8*)(hbf + (size_t)row * 256 + r16 * 16 + 8);
  float d1 = 0.f, d2 = 0.f;
  #pragma unroll
  for (int e = 0; e < 8; ++e){
    const float v0 = bf2f((u16)h0[e]), v1 = bf2f((u16)h1[e]);
    d1 += v0 * wao1[r16 * 16 + e] + v1 * wao1[r16 * 16 + 8 + e];
    d2 += v0 * wao2[r16 * 16 + e] + v1 * wao2[r16 * 16 + 8 + e];
  }
  d1 += __shfl_xor(d1, 1); d1 += __shfl_xor(d1, 2); d1 += __shfl_xor(d1, 4); d1 += __shfl_xor(d1, 8);
  d2 += __shfl_xor(d2, 1); d2 += __shfl_xor(d2, 2); d2 += __shfl_xor(d2, 4); d2 += __shfl_xor(d2, 8);
  const float d1s = d1 * LOG2E, d2s = d2 * LOG2E;
  if (r16 == 0){
    f1s[row] = d1s;
    f2s[row] = d2s;
  }
  float m = d2s;
  m = fmaxf(m, __shfl_xor(m, 16)); m = fmaxf(m, __shfl_xor(m, 32));
  if (lane == 0) atomicMax(fkey, fkey_enc(m));
}

// ---------------- GEMM: outT[c][i] = sum_k A[c][k]*B[i][k]; 16 B-rows/wave ----------------
__global__ __launch_bounds__(256) void k_gemm_at(const u16* __restrict__ A_all, const u16* __restrict__ B,
                                                 u16* __restrict__ outT_all, int K){
  const int head = blockIdx.y;
  const u16* A = A_all + (size_t)head * 128 * K;
  u16* outT = outT_all + (size_t)head * 128 * N;
  const int lane = threadIdx.x & 63, w = threadIdx.x >> 6;
  const int r16 = lane & 15, g4 = lane >> 4;
  const size_t ib = (size_t)blockIdx.x * 64 + w * 16;
  f32x4 acc[8];
  #pragma unroll
  for (int cg = 0; cg < 8; ++cg) acc[cg] = (f32x4){0,0,0,0};
  for (int kk = 0; kk < K; kk += 32){
    bf16x8 b = *(const bf16x8*)(B + (ib + r16) * (size_t)K + kk + g4 * 8);
    #pragma unroll
    for (int cg = 0; cg < 8; ++cg){
      bf16x8 a = *(const bf16x8*)(A + (size_t)(cg * 16 + r16) * K + kk + g4 * 8);
      acc[cg] = mfma16(a, b, acc[cg]);
    }
  }
  #pragma unroll
  for (int cg = 0; cg < 8; ++cg)
    #pragma unroll
    for (int q = 0; q < 4; ++q)
      outT[(size_t)(cg * 16 + g4 * 4 + q) * N + ib + r16] = f2bf(acc[cg][q]);
}

// ---------------- attention: 16 rows/wave, 4 waves/block (shared whT tile via L1) ----------------
// PART tile layout (per 16-row tile, 2048 u16): elem(r,c) at ((c>>4)*4 + (r&3))*64 + (r>>2)*16 + (c&15)
// -> every wave store is 64 lanes x 2B contiguous (128B full line).
template<int S>
__global__ __launch_bounds__(256, 4) void k_attn(
    const unsigned char* __restrict__ pk,
    const u16* __restrict__ whT_all,
    const float* __restrict__ f1_all, const float* __restrict__ f2_all,
    const unsigned int* __restrict__ fkey,
    u16* __restrict__ part, float* __restrict__ pl)
{
  const int h = blockIdx.z;
  const int s = blockIdx.y;
  const u16* whT = whT_all + (size_t)h * 128 * N;
  const float* f2 = f2_all + (size_t)h * N;
  const float fmax = fkey_dec(fkey[h]);
  const int w = threadIdx.x >> 6;
  const int lane = threadIdx.x & 63;
  const int r16 = lane & 15, g4 = lane >> 4;
  const int tile_row = blockIdx.x * 4 + w;
  const size_t ibase = (size_t)tile_row * 16;
  const int t0 = (s * 128) / S, t1 = ((s + 1) * 128) / S;

  const float f1v = f1_all[(size_t)h * N + ibase + r16];
  const float y = f1v + fmax;
  const float mrow = fmaxf(y, 0.2f * y);
  const float c1 = f1v - mrow;
  const float c2 = fmaf(0.2f, f1v, -mrow);
  f32x4 acc[8];
  f32x4 accl = (f32x4){0,0,0,0};
  #pragma unroll
  for (int ct = 0; ct < 8; ++ct) acc[ct] = (f32x4){0,0,0,0};
  bf16x8 ones;
  #pragma unroll
  for (int e = 0; e < 8; ++e) ones[e] = (short)0x3F80;

  const unsigned char* pkr = pk + (ibase + r16) * 1024 + g4 * 2;
  const float* f2p = f2 + g4 * 8;
  unsigned int bc = *(const unsigned short*)(pkr + t0 * 8);
  f32x4 f2r0 = *(const f32x4*)(f2p + t0 * 64);
  f32x4 f2r1 = *(const f32x4*)(f2p + t0 * 64 + 4);
  f32x4 f2r2 = *(const f32x4*)(f2p + t0 * 64 + 32);
  f32x4 f2r3 = *(const f32x4*)(f2p + t0 * 64 + 36);

  for (int t = t0; t < t1; ++t){
    const u16* bp = whT + (size_t)r16 * N + t * 64 + g4 * 8;
    bf16x8 b0[8];
    #pragma unroll
    for (int ct = 0; ct < 8; ++ct) b0[ct] = *(const bf16x8*)(bp + (size_t)ct * 16 * N);
    unsigned int bn; f32x4 f2n0, f2n1, f2n2, f2n3;
    if (t + 1 < t1){
      bn = *(const unsigned short*)(pkr + (t + 1) * 8);
      f2n0 = *(const f32x4*)(f2p + (t + 1) * 64);
      f2n1 = *(const f32x4*)(f2p + (t + 1) * 64 + 4);
      f2n2 = *(const f32x4*)(f2p + (t + 1) * 64 + 32);
      f2n3 = *(const f32x4*)(f2p + (t + 1) * 64 + 36);
    } else {
      bn = bc; f2n0 = f2r0; f2n1 = f2r1; f2n2 = f2r2; f2n3 = f2r3;
    }
    bf16x8 pa[2];
    #pragma unroll
    for (int k2 = 0; k2 < 2; ++k2){
      const f32x4 fa = k2 ? f2r2 : f2r0;
      const f32x4 fb = k2 ? f2r3 : f2r1;
      const float fsv[8] = {fa[0], fa[1], fa[2], fa[3], fb[0], fb[1], fb[2], fb[3]};
      const unsigned int bb = (bc >> (k2 * 8)) & 0xFFu;
      union { __hip_bfloat162 h2[4]; bf16x8 v8; } u;
      #pragma unroll
      for (int xp = 0; xp < 4; ++xp){
        const float s0 = fsv[2 * xp], s1 = fsv[2 * xp + 1];
        float p0 = __builtin_amdgcn_exp2f(fmaxf(s0 + c1, fmaf(s0, 0.2f, c2)));
        float p1 = __builtin_amdgcn_exp2f(fmaxf(s1 + c1, fmaf(s1, 0.2f, c2)));
        p0 = ((bb >> (2 * xp)) & 1u) ? p0 : 0.f;
        p1 = ((bb >> (2 * xp + 1)) & 1u) ? p1 : 0.f;
        u.h2[xp] = __float22bfloat162_rn(make_float2(p0, p1));
      }
      pa[k2] = u.v8;
      accl = mfma16(pa[k2], ones, accl);
    }
    #pragma unroll
    for (int ct = 0; ct < 8; ++ct)
      acc[ct] = mfma16(pa[0], b0[ct], acc[ct]);
    #pragma unroll
    for (int ct = 0; ct < 8; ++ct){
      bf16x8 b1 = *(const bf16x8*)(bp + (size_t)ct * 16 * N + 32);
      acc[ct] = mfma16(pa[1], b1, acc[ct]);
    }
    bc = bn; f2r0 = f2n0; f2r1 = f2n1; f2r2 = f2n2; f2r3 = f2n3;
  }

  const int plane = h * S + s;
  u16* pp = part + ((size_t)plane * 512 + tile_row) * 2048;
  #pragma unroll
  for (int ct = 0; ct < 8; ++ct)
    #pragma unroll
    for (int q = 0; q < 4; ++q)
      pp[(ct * 4 + q) * 64 + lane] = f2bf(acc[ct][q]);
  if (r16 == 0){
    #pragma unroll
    for (int q = 0; q < 4; ++q)
      pl[(size_t)plane * N + ibase + g4 * 4 + q] = accl[q];
  }
}

// ---------------- merge partials: sum, normalize, elu, write ----------------
template<int S, bool L2>
__global__ __launch_bounds__(256) void k_attn_merge(
    const u16* __restrict__ part, const float* __restrict__ pl,
    u16* __restrict__ hbf, float* __restrict__ nodeout, u16* __restrict__ comb)
{
  const int h = blockIdx.y;
  const int idx = blockIdx.x * 256 + threadIdx.x;
  const int i = idx >> 5, c4 = (idx & 31) * 4;
  const int tile = i >> 4, r = i & 15;
  const size_t off = (size_t)tile * 2048 + (size_t)(((c4 >> 4) * 4 + (r & 3)) * 64 + ((r >> 2) & 3) * 16 + (c4 & 15));
  f32x4 a = (f32x4){0,0,0,0};
  float L = 0.f;
  #pragma unroll
  for (int s = 0; s < S; ++s){
    const size_t plane = h * S + s;
    u16x4 v = *(const u16x4*)(part + plane * (size_t)(N * 128) + off);
    a[0] += bf2f(v[0]); a[1] += bf2f(v[1]); a[2] += bf2f(v[2]); a[3] += bf2f(v[3]);
    L += pl[plane * (size_t)N + i];
  }
  const float linv = 1.f / L;
  u16x4 hv;
  #pragma unroll
  for (int e = 0; e < 4; ++e){
    float o = a[e] * linv;
    o = (o > 0.f) ? o : (__expf(o) - 1.f);
    a[e] = o;
    hv[e] = f2bf(o);
  }
  if constexpr (!L2){
    *(u16x4*)(hbf + (size_t)i * 256 + h * 128 + c4) = hv;
  } else {
    *(f32x4*)(nodeout + (size_t)i * 128 + c4) = a;
    *(u16x4*)(comb + (size_t)i * 256 + 128 + c4) = hv;
  }
}

// ---------------- row-major GEMM + bias + relu (+optional column-sum) ----------------
template<bool STORE, bool COLSUM>
__global__ __launch_bounds__(256) void k_gemm_row(
    const u16* __restrict__ A, const u16* __restrict__ BT,
    const float* __restrict__ bias,
    u16* __restrict__ out, float* __restrict__ csum,
    int K, int Ntot)
{
  const int lane = threadIdx.x & 63, w = threadIdx.x >> 6;
  const int r16 = lane & 15, g4 = lane >> 4;
  const size_t rbase = (size_t)blockIdx.x * 64 + w * 16;
  const int cbase = blockIdx.y * 128;
  f32x4 acc[8];
  #pragma unroll
  for (int ct = 0; ct < 8; ++ct) acc[ct] = (f32x4){0,0,0,0};
  for (int kk = 0; kk < K; kk += 32){
    bf16x8 af = *(const bf16x8*)(A + (rbase + r16) * (size_t)K + kk + g4 * 8);
    #pragma unroll
    for (int ct = 0; ct < 8; ++ct){
      bf16x8 bfr = *(const bf16x8*)(BT + (size_t)(cbase + ct * 16 + r16) * K + kk + g4 * 8);
      acc[ct] = mfma16(af, bfr, acc[ct]);
    }
  }
  #pragma unroll
  for (int ct = 0; ct < 8; ++ct){
    const float bv = bias[cbase + ct * 16 + r16];
    float sacc = 0.f;
    #pragma unroll
    for (int q = 0; q < 4; ++q){
      float v = acc[ct][q] + bv;
      v = fmaxf(v, 0.f);
      if constexpr (STORE)
        out[(rbase + g4 * 4 + q) * (size_t)Ntot + cbase + ct * 16 + r16] = f2bf(v);
      sacc += v;
    }
    if constexpr (COLSUM){
      sacc += __shfl_xor(sacc, 16); sacc += __shfl_xor(sacc, 32);
      if (lane < 16) atomicAdd(&csum[cbase + ct * 16 + lane], sacc);
    }
  }
}

__global__ void k_final(const float* __restrict__ csum, float* __restrict__ out){
  out[threadIdx.x] = csum[threadIdx.x] * (1.f / 8192.f);
}

// ---------------- host launch ----------------
extern "C" void kernel_launch(void* const* d_in, const int* in_sizes, int n_in,
                              void* d_out, int out_size, void* d_ws, size_t ws_size,
                              hipStream_t stream) {
  const int*   adj = (const int*)d_in[0];
  const float* x   = (const float*)d_in[1];
  const float* Wh  = (const float*)d_in[2];
  const float* ah  = (const float*)d_in[3];
  const float* Wo  = (const float*)d_in[4];
  const float* ao  = (const float*)d_in[5];
  const float* g1  = (const float*)d_in[6];
  const float* b1  = (const float*)d_in[7];
  const float* g2  = (const float*)d_in[8];
  const float* b2  = (const float*)d_in[9];
  float* outp = (float*)d_out;
  char* ws = (char*)d_ws;

  constexpr size_t PK   = 0;          //  8,388,608  packed adj bits (permuted)
  constexpr size_t PART = 8388608;    // 25,165,824  bf16 partials [12 planes][512 tiles][2048]
  constexpr size_t PL   = 33554432;   //    393,216  l partials [12][8192] f32
  constexpr size_t XBF  = 33947648;   //  2,097,152  x bf16
  constexpr size_t WHT1 = 36044800;   //  4,194,304  Wh^T layer1 [2][128][8192]
  constexpr size_t WHT2 = 40239104;   //  2,097,152  Wh^T layer2 [128][8192]
  constexpr size_t HBF  = 42336256;   //  4,194,304  h bf16 [8192][256]
  constexpr size_t COMB = 46530560;   //  4,194,304  combined [8192][256]
  constexpr size_t H1RO = 50724864;   //  4,194,304  readout hidden [8192][256]
  constexpr size_t F1S  = 54919168;   //     65,536  [2][8192] f32 (scaled)
  constexpr size_t F2S  = 54984704;   //     65,536
  constexpr size_t CSUM = 55050240;   //        512
  constexpr size_t WTH  = 55051008;   //     65,536  W_heads^T bf16 [2][128][128]
  constexpr size_t WOT  = 55116544;   //     65,536  W_out^T bf16 [128][256]
  constexpr size_t G1T  = 55182080;   //    131,072
  constexpr size_t G2T  = 55313152;   //     65,536
  constexpr size_t WA   = 55378688;   //      4,096
  constexpr size_t FKEY = 55382784;   //         16  keyed fmax [0,1]=L1 heads, [2]=L2

  k_pack<<<2048, 256, 0, stream>>>(adj, (unsigned long long*)(ws + PK));
  k_prep<<<1668, 256, 0, stream>>>(x, Wh, Wo, g1, g2, ah, ao,
      (u16*)(ws + XBF), (u16*)(ws + COMB), (u16*)(ws + WTH), (u16*)(ws + WOT),
      (u16*)(ws + G1T), (u16*)(ws + G2T),
      (float*)(ws + WA), (unsigned int*)(ws + FKEY), (float*)(ws + CSUM));

  // layer 1
  k_gemv1<<<dim3(512, 2), 256, 0, stream>>>(x, (const float*)(ws + WA),
      (float*)(ws + F1S), (float*)(ws + F2S), (unsigned int*)(ws + FKEY));
  k_gemm_at<<<dim3(128, 2), 256, 0, stream>>>((const u16*)(ws + WTH), (const u16*)(ws + XBF),
                                              (u16*)(ws + WHT1), 128);
  k_attn<6><<<dim3(128, 6, 2), 256, 0, stream>>>(
      (const unsigned char*)(ws + PK), (const u16*)(ws + WHT1),
      (const float*)(ws + F1S), (const float*)(ws + F2S), (const unsigned int*)(ws + FKEY),
      (u16*)(ws + PART), (float*)(ws + PL));
  k_attn_merge<6, false><<<dim3(1024, 2), 256, 0, stream>>>(
      (const u16*)(ws + PART), (const float*)(ws + PL),
      (u16*)(ws + HBF), nullptr, nullptr);

  // layer 2
  k_gemv2<<<dim3(512, 1), 256, 0, stream>>>((const u16*)(ws + HBF),
      (const float*)(ws + WA) + 512, (const float*)(ws + WA) + 768,
      (float*)(ws + F1S), (float*)(ws + F2S), (unsigned int*)(ws + FKEY) + 2);
  k_gemm_at<<<dim3(128, 1), 256, 0, stream>>>((const u16*)(ws + WOT), (const u16*)(ws + HBF),
                                              (u16*)(ws + WHT2), 256);
  k_attn<12><<<dim3(128, 12, 1), 256, 0, stream>>>(
      (const unsigned char*)(ws + PK), (const u16*)(ws + WHT2),
      (const float*)(ws + F1S), (const float*)(ws + F2S), (const unsigned int*)(ws + FKEY) + 2,
      (u16*)(ws + PART), (float*)(ws + PL));
  k_attn_merge<12, true><<<dim3(1024, 1), 256, 0, stream>>>(
      (const u16*)(ws + PART), (const float*)(ws + PL),
      nullptr, outp, (u16*)(ws + COMB));

  // readout MLP
  k_gemm_row<true, false><<<dim3(128, 2), 256, 0, stream>>>(
      (const u16*)(ws + COMB), (const u16*)(ws + G1T), b1,
      (u16*)(ws + H1RO), nullptr, 256, 256);
  k_gemm_row<false, true><<<dim3(128, 1), 256, 0, stream>>>(
      (const u16*)(ws + H1RO), (const u16*)(ws + G2T), b2,
      nullptr, (float*)(ws + CSUM), 256, 128);
  k_final<<<1, 128, 0, stream>>>((const float*)(ws + CSUM), outp + (size_t)N * 128);
}

// Round 5
// 690.225 us; speedup vs baseline: 1.4698x; 1.4698x over previous
//
#include <hip/hip_runtime.h>
#include <hip/hip_bf16.h>

typedef unsigned short u16;
typedef __attribute__((ext_vector_type(4))) float f32x4;
typedef __attribute__((ext_vector_type(8))) short bf16x8;
typedef __attribute__((ext_vector_type(4))) unsigned short u16x4;

#define N 8192
#define LOG2E 1.4426950408889634f

__device__ __forceinline__ float bf2f(u16 u){
  union { float f; unsigned int i; } v; v.i = ((unsigned int)u) << 16; return v.f;
}
__device__ __forceinline__ u16 f2bf(float f){
  union { float f; unsigned int i; } v; v.f = f;
  unsigned int r = v.i + 0x7fffu + ((v.i >> 16) & 1u);
  return (u16)(r >> 16);
}
__device__ __forceinline__ f32x4 mfma16(bf16x8 a, bf16x8 b, f32x4 c){
  return __builtin_amdgcn_mfma_f32_16x16x32_bf16(a, b, c, 0, 0, 0);
}
__device__ __forceinline__ unsigned int fkey_enc(float f){
  unsigned int u = __float_as_uint(f);
  return (u & 0x80000000u) ? ~u : (u | 0x80000000u);
}
__device__ __forceinline__ float fkey_dec(unsigned int k){
  unsigned int u = (k & 0x80000000u) ? (k ^ 0x80000000u) : ~k;
  return __uint_as_float(u);
}
// async global->LDS, 16B per lane; lds dest is wave-uniform base (+lane*16 by HW)
__device__ __forceinline__ void gload16(const void* g, void* l){
  __builtin_amdgcn_global_load_lds(
      (const __attribute__((address_space(1))) unsigned int*)(g),
      (__attribute__((address_space(3))) unsigned int*)(l), 16, 0, 0);
}

// ---------------- pack adj (int32 0/1) -> bitmask [N][1024B] (raw order) ----------------
__global__ __launch_bounds__(256) void k_pack(const int* __restrict__ adj,
                                              unsigned long long* __restrict__ packed){
  const int wid = blockIdx.x * 4 + (threadIdx.x >> 6);
  const int lane = threadIdx.x & 63;
  const size_t base = (size_t)wid * 128;
  #pragma unroll 4
  for (int g = 0; g < 128; ++g){
    const size_t grp = base + g;
    const int v = adj[grp * 64 + lane];
    const unsigned long long m = __ballot(v != 0);
    if (lane == 0) packed[grp] = m;
  }
}

// ---------------- fused prep: x->bf16(+comb), 4 transposes, wa vectors, zero-init ----------------
__global__ __launch_bounds__(256) void k_prep(
    const float* __restrict__ x, const float* __restrict__ Wh, const float* __restrict__ Wo,
    const float* __restrict__ g1, const float* __restrict__ g2,
    const float* __restrict__ ah, const float* __restrict__ ao,
    u16* __restrict__ xbf, u16* __restrict__ comb,
    u16* __restrict__ wth, u16* __restrict__ wot,
    u16* __restrict__ g1t, u16* __restrict__ g2t,
    float* __restrict__ wa, unsigned int* __restrict__ fkey, float* __restrict__ csum)
{
  const int b = blockIdx.x, t = threadIdx.x;
  if (b < 1024){                                  // x -> xbf + comb[:, :128]
    const int idx = b * 256 + t;
    f32x4 v = ((const f32x4*)x)[idx];
    u16x4 h;
    #pragma unroll
    for (int e = 0; e < 4; ++e) h[e] = f2bf(v[e]);
    ((u16x4*)xbf)[idx] = h;
    const int i = idx >> 5, c4 = (idx & 31) * 4;
    *(u16x4*)(comb + (size_t)i * 256 + c4) = h;
  } else if (b < 1152){                           // Wh^T (2 heads)
    const int rel = (b - 1024) * 256 + t;
    const int head = rel >> 14, win = rel & 16383;
    const int n = win >> 7, k = win & 127;
    wth[rel] = f2bf(Wh[(head << 14) + k * 128 + n]);
  } else if (b < 1280){                           // Wo^T
    const int rel = (b - 1152) * 256 + t;
    const int n = rel >> 8, k = rel & 255;
    wot[rel] = f2bf(Wo[k * 128 + n]);
  } else if (b < 1536){                           // g1^T
    const int rel = (b - 1280) * 256 + t;
    const int n = rel >> 8, k = rel & 255;
    g1t[rel] = f2bf(g1[k * 256 + n]);
  } else if (b < 1664){                           // g2^T
    const int rel = (b - 1536) * 256 + t;
    const int n = rel >> 8, k = rel & 255;
    g2t[rel] = f2bf(g2[k * 128 + n]);
  } else if (b < 1667){                           // wa vectors
    const int z = b - 1664;
    if (z < 2){
      if (t < 128){
        float a1 = 0.f, a2 = 0.f;
        for (int c = 0; c < 128; ++c){
          const float w = Wh[(size_t)z * 16384 + t * 128 + c];
          a1 += w * ah[z * 256 + c];
          a2 += w * ah[z * 256 + 128 + c];
        }
        wa[z * 128 + t] = a1; wa[256 + z * 128 + t] = a2;
      }
    } else {
      if (t < 256){
        float a1 = 0.f, a2 = 0.f;
        for (int c = 0; c < 128; ++c){
          const float w = Wo[(size_t)t * 128 + c];
          a1 += w * ao[c];
          a2 += w * ao[128 + c];
        }
        wa[512 + t] = a1; wa[768 + t] = a2;
      }
    }
  } else {
    if (t < 128) csum[t] = 0.f;
    if (t < 4) fkey[t] = 0u;
  }
}

// ---------------- gemv layer1: f1s/f2s = (x @ wa) * log2e, + keyed atomic max of f2 ----------------
__global__ __launch_bounds__(256) void k_gemv1(const float* __restrict__ x, const float* __restrict__ wa,
                                               float* __restrict__ f1s, float* __restrict__ f2s,
                                               unsigned int* __restrict__ fkey){
  const int h = blockIdx.y;
  const float* wa1 = wa + h * 128;
  const float* wa2 = wa + 256 + h * 128;
  const int lane = threadIdx.x & 63, w = threadIdx.x >> 6;
  const int r16 = lane & 15, g4 = lane >> 4;
  const int row = blockIdx.x * 16 + w * 4 + g4;
  const float* xr = x + (size_t)row * 128 + r16 * 8;
  f32x4 x0 = *(const f32x4*)(xr);
  f32x4 x1 = *(const f32x4*)(xr + 4);
  f32x4 wA0 = *(const f32x4*)(wa1 + r16 * 8);
  f32x4 wA1 = *(const f32x4*)(wa1 + r16 * 8 + 4);
  f32x4 wB0 = *(const f32x4*)(wa2 + r16 * 8);
  f32x4 wB1 = *(const f32x4*)(wa2 + r16 * 8 + 4);
  float d1 = 0.f, d2 = 0.f;
  #pragma unroll
  for (int e = 0; e < 4; ++e){
    d1 += x0[e] * wA0[e] + x1[e] * wA1[e];
    d2 += x0[e] * wB0[e] + x1[e] * wB1[e];
  }
  d1 += __shfl_xor(d1, 1); d1 += __shfl_xor(d1, 2); d1 += __shfl_xor(d1, 4); d1 += __shfl_xor(d1, 8);
  d2 += __shfl_xor(d2, 1); d2 += __shfl_xor(d2, 2); d2 += __shfl_xor(d2, 4); d2 += __shfl_xor(d2, 8);
  const float d1s = d1 * LOG2E, d2s = d2 * LOG2E;
  if (r16 == 0){
    f1s[(size_t)h * N + row] = d1s;
    f2s[(size_t)h * N + row] = d2s;
  }
  float m = d2s;
  m = fmaxf(m, __shfl_xor(m, 16)); m = fmaxf(m, __shfl_xor(m, 32));
  if (lane == 0) atomicMax(fkey + h, fkey_enc(m));
}

// ---------------- gemv layer2 (+ keyed atomic max) ----------------
__global__ __launch_bounds__(256) void k_gemv2(const u16* __restrict__ hbf,
                                               const float* __restrict__ wao1, const float* __restrict__ wao2,
                                               float* __restrict__ f1s, float* __restrict__ f2s,
                                               unsigned int* __restrict__ fkey){
  const int lane = threadIdx.x & 63, w = threadIdx.x >> 6;
  const int r16 = lane & 15, g4 = lane >> 4;
  const int row = blockIdx.x * 16 + w * 4 + g4;
  bf16x8 h0 = *(const bf16x8*)(hbf + (size_t)row * 256 + r16 * 16);
  bf16x8 h1 = *(const bf16x8*)(hbf + (size_t)row * 256 + r16 * 16 + 8);
  float d1 = 0.f, d2 = 0.f;
  #pragma unroll
  for (int e = 0; e < 8; ++e){
    const float v0 = bf2f((u16)h0[e]), v1 = bf2f((u16)h1[e]);
    d1 += v0 * wao1[r16 * 16 + e] + v1 * wao1[r16 * 16 + 8 + e];
    d2 += v0 * wao2[r16 * 16 + e] + v1 * wao2[r16 * 16 + 8 + e];
  }
  d1 += __shfl_xor(d1, 1); d1 += __shfl_xor(d1, 2); d1 += __shfl_xor(d1, 4); d1 += __shfl_xor(d1, 8);
  d2 += __shfl_xor(d2, 1); d2 += __shfl_xor(d2, 2); d2 += __shfl_xor(d2, 4); d2 += __shfl_xor(d2, 8);
  const float d1s = d1 * LOG2E, d2s = d2 * LOG2E;
  if (r16 == 0){
    f1s[row] = d1s;
    f2s[row] = d2s;
  }
  float m = d2s;
  m = fmaxf(m, __shfl_xor(m, 16)); m = fmaxf(m, __shfl_xor(m, 32));
  if (lane == 0) atomicMax(fkey, fkey_enc(m));
}

// ---------------- GEMM -> tiled-swizzled whT: per head, 128 tiles of 16KB ----------------
// tile t holds channels c=0..127 x j'=0..63 (j = t*64+j'), u16 index within tile:
//   c*64 + (j' ^ ((c&7)<<3))
__global__ __launch_bounds__(256) void k_gemm_at(const u16* __restrict__ A_all, const u16* __restrict__ B,
                                                 u16* __restrict__ outT_all, int K){
  const int head = blockIdx.y;
  const u16* A = A_all + (size_t)head * 128 * K;
  u16* outT = outT_all + (size_t)head * 1048576;
  const int lane = threadIdx.x & 63, w = threadIdx.x >> 6;
  const int r16 = lane & 15, g4 = lane >> 4;
  const size_t ib = (size_t)blockIdx.x * 64 + w * 16;
  f32x4 acc[8];
  #pragma unroll
  for (int cg = 0; cg < 8; ++cg) acc[cg] = (f32x4){0,0,0,0};
  for (int kk = 0; kk < K; kk += 32){
    bf16x8 b = *(const bf16x8*)(B + (ib + r16) * (size_t)K + kk + g4 * 8);
    #pragma unroll
    for (int cg = 0; cg < 8; ++cg){
      bf16x8 a = *(const bf16x8*)(A + (size_t)(cg * 16 + r16) * K + kk + g4 * 8);
      acc[cg] = mfma16(a, b, acc[cg]);
    }
  }
  const int jp = w * 16 + r16;           // j' within tile (tile = blockIdx.x)
  u16* tb = outT + (size_t)blockIdx.x * 8192;
  #pragma unroll
  for (int cg = 0; cg < 8; ++cg)
    #pragma unroll
    for (int q = 0; q < 4; ++q){
      const int c = cg * 16 + g4 * 4 + q;
      tb[c * 64 + (jp ^ ((c & 7) << 3))] = f2bf(acc[cg][q]);
    }
}

// ---------------- attention: LDS-staged whT tiles, 4 waves/block x 32 rows ----------------
template<int S>
__global__ __launch_bounds__(256, 4) void k_attn(
    const unsigned char* __restrict__ pk,
    const u16* __restrict__ whT_all,       // tiled-swizzled [H][128][8192] u16
    const float* __restrict__ f1_all, const float* __restrict__ f2_all,
    const unsigned int* __restrict__ fkey,
    u16* __restrict__ part, float* __restrict__ pl)
{
  __shared__ __align__(16) u16 tile[2][8192];   // 2 x 16 KB
  const int h = blockIdx.z;
  const int s = blockIdx.y;
  const float* f2 = f2_all + (size_t)h * N;
  const float fmax = fkey_dec(fkey[h]);
  const int w = threadIdx.x >> 6;
  const int lane = threadIdx.x & 63;
  const int r16 = lane & 15, g4 = lane >> 4;
  const size_t ibase = (size_t)blockIdx.x * 128 + w * 32;
  constexpr int TPS = 128 / S;
  const int t0 = s * TPS, t1 = t0 + TPS;
  const char* gt = (const char*)whT_all + (size_t)h * 2097152;

  float c1[2], c2[2], lsum[2];
  f32x4 acc[2][8];
  #pragma unroll
  for (int rg = 0; rg < 2; ++rg){
    const float f1v = f1_all[(size_t)h * N + ibase + rg * 16 + r16];
    const float y = f1v + fmax;
    const float mrow = fmaxf(y, 0.2f * y);
    c1[rg] = f1v - mrow;
    c2[rg] = fmaf(0.2f, f1v, -mrow);
    lsum[rg] = 0.f;
    #pragma unroll
    for (int ct = 0; ct < 8; ++ct) acc[rg][ct] = (f32x4){0,0,0,0};
  }

  // per-lane swizzled LDS read offsets (u16 units): addr = off[kk] + ct*1024
  const int swz = (r16 & 7) << 3;
  const int off0 = r16 * 64 + ((g4 * 8) ^ swz);
  const int off1 = r16 * 64 + ((32 | (g4 * 8)) ^ swz);

  // stage tile tt into LDS buf (each wave loads its 4KB quarter)
  auto stage = [&](int buf, int tt){
    const char* src = gt + (size_t)tt * 16384 + w * 4096 + lane * 16;
    char* dst = ((char*)&tile[0][0]) + buf * 16384 + w * 4096;
    #pragma unroll
    for (int k = 0; k < 4; ++k)
      gload16(src + k * 1024, dst + k * 1024);
  };

  stage(0, t0);
  for (int t = t0; t < t1; ++t){
    const int cur = (t - t0) & 1;
    __syncthreads();                       // drains vm/lgkm: tile[cur] ready, tile[cur^1] free
    if (t + 1 < t1) stage(cur ^ 1, t + 1); // overlap next-tile DMA with compute
    // scalar inputs for this tile
    const int j0 = t * 64;
    float fs[16];
    *(f32x4*)&fs[0]  = *(const f32x4*)(f2 + j0 + g4 * 8);
    *(f32x4*)&fs[4]  = *(const f32x4*)(f2 + j0 + g4 * 8 + 4);
    *(f32x4*)&fs[8]  = *(const f32x4*)(f2 + j0 + 32 + g4 * 8);
    *(f32x4*)&fs[12] = *(const f32x4*)(f2 + j0 + 32 + g4 * 8 + 4);
    unsigned int bits[2][2];
    #pragma unroll
    for (int rg = 0; rg < 2; ++rg){
      const size_t rb = (ibase + rg * 16 + r16) * 1024 + t * 8;
      bits[rg][0] = pk[rb + g4];
      bits[rg][1] = pk[rb + 4 + g4];
    }
    // scores -> pa
    bf16x8 pa[2][2];
    #pragma unroll
    for (int rg = 0; rg < 2; ++rg){
      #pragma unroll
      for (int k2 = 0; k2 < 2; ++k2){
        float pv[8];
        #pragma unroll
        for (int x = 0; x < 8; ++x){
          const float sv = fs[k2 * 8 + x];
          const float p = __builtin_amdgcn_exp2f(fmaxf(sv + c1[rg], fmaf(sv, 0.2f, c2[rg])));
          pv[x] = ((bits[rg][k2] >> x) & 1u) ? p : 0.f;
          lsum[rg] += pv[x];
        }
        union { __hip_bfloat162 h2[4]; bf16x8 v8; } u;
        u.h2[0] = __float22bfloat162_rn(make_float2(pv[0], pv[1]));
        u.h2[1] = __float22bfloat162_rn(make_float2(pv[2], pv[3]));
        u.h2[2] = __float22bfloat162_rn(make_float2(pv[4], pv[5]));
        u.h2[3] = __float22bfloat162_rn(make_float2(pv[6], pv[7]));
        pa[rg][k2] = u.v8;
      }
    }
    // PV from LDS
    const u16* lp = &tile[cur][0];
    #pragma unroll
    for (int ct = 0; ct < 8; ++ct){
      bf16x8 b0 = *(const bf16x8*)(lp + off0 + ct * 1024);
      acc[0][ct] = mfma16(pa[0][0], b0, acc[0][ct]);
      acc[1][ct] = mfma16(pa[1][0], b0, acc[1][ct]);
    }
    #pragma unroll
    for (int ct = 0; ct < 8; ++ct){
      bf16x8 b1 = *(const bf16x8*)(lp + off1 + ct * 1024);
      acc[0][ct] = mfma16(pa[0][1], b1, acc[0][ct]);
      acc[1][ct] = mfma16(pa[1][1], b1, acc[1][ct]);
    }
  }

  const int plane = h * S + s;
  u16* pp = part + (size_t)plane * (size_t)(N * 128);
  #pragma unroll
  for (int rg = 0; rg < 2; ++rg){
    float lv = lsum[rg];
    lv += __shfl_xor(lv, 16); lv += __shfl_xor(lv, 32);
    if (lane < 16) pl[(size_t)plane * N + ibase + rg * 16 + lane] = lv;
    #pragma unroll
    for (int ct = 0; ct < 8; ++ct)
      #pragma unroll
      for (int q = 0; q < 4; ++q)
        pp[(ibase + rg * 16 + g4 * 4 + q) * 128 + ct * 16 + r16] = f2bf(acc[rg][ct][q]);
  }
}

// ---------------- merge partials: sum, normalize, elu, write ----------------
template<int S, bool L2>
__global__ __launch_bounds__(256) void k_attn_merge(
    const u16* __restrict__ part, const float* __restrict__ pl,
    u16* __restrict__ hbf, float* __restrict__ nodeout, u16* __restrict__ comb)
{
  const int h = blockIdx.y;
  const int idx = blockIdx.x * 256 + threadIdx.x;
  const int i = idx >> 5, c4 = (idx & 31) * 4;
  f32x4 a = (f32x4){0,0,0,0};
  float L = 0.f;
  #pragma unroll
  for (int s = 0; s < S; ++s){
    const size_t plane = h * S + s;
    u16x4 v = *(const u16x4*)(part + plane * (size_t)(N * 128) + (size_t)i * 128 + c4);
    a[0] += bf2f(v[0]); a[1] += bf2f(v[1]); a[2] += bf2f(v[2]); a[3] += bf2f(v[3]);
    L += pl[plane * (size_t)N + i];
  }
  const float linv = 1.f / L;
  u16x4 hv;
  #pragma unroll
  for (int e = 0; e < 4; ++e){
    float o = a[e] * linv;
    o = (o > 0.f) ? o : (__expf(o) - 1.f);
    a[e] = o;
    hv[e] = f2bf(o);
  }
  if constexpr (!L2){
    *(u16x4*)(hbf + (size_t)i * 256 + h * 128 + c4) = hv;
  } else {
    *(f32x4*)(nodeout + (size_t)i * 128 + c4) = a;
    *(u16x4*)(comb + (size_t)i * 256 + 128 + c4) = hv;
  }
}

// ---------------- row-major GEMM + bias + relu (+optional column-sum) ----------------
template<bool STORE, bool COLSUM>
__global__ __launch_bounds__(256) void k_gemm_row(
    const u16* __restrict__ A, const u16* __restrict__ BT,
    const float* __restrict__ bias,
    u16* __restrict__ out, float* __restrict__ csum,
    int K, int Ntot)
{
  const int lane = threadIdx.x & 63, w = threadIdx.x >> 6;
  const int r16 = lane & 15, g4 = lane >> 4;
  const size_t rbase = (size_t)blockIdx.x * 64 + w * 16;
  const int cbase = blockIdx.y * 128;
  f32x4 acc[8];
  #pragma unroll
  for (int ct = 0; ct < 8; ++ct) acc[ct] = (f32x4){0,0,0,0};
  for (int kk = 0; kk < K; kk += 32){
    bf16x8 af = *(const bf16x8*)(A + (rbase + r16) * (size_t)K + kk + g4 * 8);
    #pragma unroll
    for (int ct = 0; ct < 8; ++ct){
      bf16x8 bfr = *(const bf16x8*)(BT + (size_t)(cbase + ct * 16 + r16) * K + kk + g4 * 8);
      acc[ct] = mfma16(af, bfr, acc[ct]);
    }
  }
  #pragma unroll
  for (int ct = 0; ct < 8; ++ct){
    const float bv = bias[cbase + ct * 16 + r16];
    float sacc = 0.f;
    #pragma unroll
    for (int q = 0; q < 4; ++q){
      float v = acc[ct][q] + bv;
      v = fmaxf(v, 0.f);
      if constexpr (STORE)
        out[(rbase + g4 * 4 + q) * (size_t)Ntot + cbase + ct * 16 + r16] = f2bf(v);
      sacc += v;
    }
    if constexpr (COLSUM){
      sacc += __shfl_xor(sacc, 16); sacc += __shfl_xor(sacc, 32);
      if (lane < 16) atomicAdd(&csum[cbase + ct * 16 + lane], sacc);
    }
  }
}

__global__ void k_final(const float* __restrict__ csum, float* __restrict__ out){
  out[threadIdx.x] = csum[threadIdx.x] * (1.f / 8192.f);
}

// ---------------- host launch ----------------
extern "C" void kernel_launch(void* const* d_in, const int* in_sizes, int n_in,
                              void* d_out, int out_size, void* d_ws, size_t ws_size,
                              hipStream_t stream) {
  const int*   adj = (const int*)d_in[0];
  const float* x   = (const float*)d_in[1];
  const float* Wh  = (const float*)d_in[2];
  const float* ah  = (const float*)d_in[3];
  const float* Wo  = (const float*)d_in[4];
  const float* ao  = (const float*)d_in[5];
  const float* g1  = (const float*)d_in[6];
  const float* b1  = (const float*)d_in[7];
  const float* g2  = (const float*)d_in[8];
  const float* b2  = (const float*)d_in[9];
  float* outp = (float*)d_out;
  char* ws = (char*)d_ws;

  constexpr size_t PK   = 0;          //  8,388,608  packed adj bits
  constexpr size_t PART = 8388608;    // 33,554,432  bf16 partials [16 planes][8192][128]
  constexpr size_t PL   = 41943040;   //    524,288  l partials [16][8192] f32
  constexpr size_t XBF  = 42467328;   //  2,097,152  x bf16
  constexpr size_t WHT1 = 44564480;   //  4,194,304  Wh^T L1 tiled-swz [2][128][8192]u16
  constexpr size_t WHT2 = 48758784;   //  2,097,152  Wh^T L2 tiled-swz
  constexpr size_t HBF  = 50855936;   //  4,194,304  h bf16 [8192][256]
  constexpr size_t COMB = 55050240;   //  4,194,304  combined [8192][256]
  constexpr size_t H1RO = WHT1;       //  alias: WhT1 dead after attn1, H1RO used after attn2
  constexpr size_t F1S  = 59244544;   //     65,536
  constexpr size_t F2S  = 59310080;   //     65,536
  constexpr size_t CSUM = 59375616;   //        512
  constexpr size_t WTH  = 59376128;   //     65,536  W_heads^T bf16 [2][128][128]
  constexpr size_t WOT  = 59441664;   //     65,536  W_out^T bf16 [128][256]
  constexpr size_t G1T  = 59507200;   //    131,072
  constexpr size_t G2T  = 59638272;   //     65,536
  constexpr size_t WA   = 59703808;   //      4,096
  constexpr size_t FKEY = 59707904;   //         16

  k_pack<<<2048, 256, 0, stream>>>(adj, (unsigned long long*)(ws + PK));
  k_prep<<<1668, 256, 0, stream>>>(x, Wh, Wo, g1, g2, ah, ao,
      (u16*)(ws + XBF), (u16*)(ws + COMB), (u16*)(ws + WTH), (u16*)(ws + WOT),
      (u16*)(ws + G1T), (u16*)(ws + G2T),
      (float*)(ws + WA), (unsigned int*)(ws + FKEY), (float*)(ws + CSUM));

  // layer 1
  k_gemv1<<<dim3(512, 2), 256, 0, stream>>>(x, (const float*)(ws + WA),
      (float*)(ws + F1S), (float*)(ws + F2S), (unsigned int*)(ws + FKEY));
  k_gemm_at<<<dim3(128, 2), 256, 0, stream>>>((const u16*)(ws + WTH), (const u16*)(ws + XBF),
                                              (u16*)(ws + WHT1), 128);
  k_attn<8><<<dim3(64, 8, 2), 256, 0, stream>>>(
      (const unsigned char*)(ws + PK), (const u16*)(ws + WHT1),
      (const float*)(ws + F1S), (const float*)(ws + F2S), (const unsigned int*)(ws + FKEY),
      (u16*)(ws + PART), (float*)(ws + PL));
  k_attn_merge<8, false><<<dim3(1024, 2), 256, 0, stream>>>(
      (const u16*)(ws + PART), (const float*)(ws + PL),
      (u16*)(ws + HBF), nullptr, nullptr);

  // layer 2
  k_gemv2<<<dim3(512, 1), 256, 0, stream>>>((const u16*)(ws + HBF),
      (const float*)(ws + WA) + 512, (const float*)(ws + WA) + 768,
      (float*)(ws + F1S), (float*)(ws + F2S), (unsigned int*)(ws + FKEY) + 2);
  k_gemm_at<<<dim3(128, 1), 256, 0, stream>>>((const u16*)(ws + WOT), (const u16*)(ws + HBF),
                                              (u16*)(ws + WHT2), 256);
  k_attn<16><<<dim3(64, 16, 1), 256, 0, stream>>>(
      (const unsigned char*)(ws + PK), (const u16*)(ws + WHT2),
      (const float*)(ws + F1S), (const float*)(ws + F2S), (const unsigned int*)(ws + FKEY) + 2,
      (u16*)(ws + PART), (float*)(ws + PL));
  k_attn_merge<16, true><<<dim3(1024, 1), 256, 0, stream>>>(
      (const u16*)(ws + PART), (const float*)(ws + PL),
      nullptr, outp, (u16*)(ws + COMB));

  // readout MLP
  k_gemm_row<true, false><<<dim3(128, 2), 256, 0, stream>>>(
      (const u16*)(ws + COMB), (const u16*)(ws + G1T), b1,
      (u16*)(ws + H1RO), nullptr, 256, 256);
  k_gemm_row<false, true><<<dim3(128, 1), 256, 0, stream>>>(
      (const u16*)(ws + H1RO), (const u16*)(ws + G2T), b2,
      nullptr, (float*)(ws + CSUM), 256, 128);
  k_final<<<1, 128, 0, stream>>>((const float*)(ws + CSUM), outp + (size_t)N * 128);
}